// Round 6
// baseline (949.243 us; speedup 1.0000x reference)
//
#include <hip/hip_runtime.h>

typedef __attribute__((ext_vector_type(8))) __bf16 bf16x8;
typedef __attribute__((ext_vector_type(4))) float f32x4;

__device__ __forceinline__ float bf2f(unsigned int u) {
    return __uint_as_float(u << 16);
}
__device__ __forceinline__ unsigned short f2bf(float f) {
    unsigned int x = __float_as_uint(f);
    return (unsigned short)((x + 0x7fffu + ((x >> 16) & 1u)) >> 16);
}

// ---------------- merged cast f32 -> bf16 ----------------
__global__ void cast_all(const float* __restrict__ ent, const float* __restrict__ rel,
                         const float* __restrict__ W,
                         unsigned short* __restrict__ X_bf,
                         unsigned short* __restrict__ W_bf) {
    int i = blockIdx.x * blockDim.x + threadIdx.x;
    const float* src;
    unsigned short* dst;
    int g;
    if (i < 262144) {
        src = ent; dst = X_bf; g = i;
    } else if (i < 266240) {
        src = rel; dst = X_bf + 2048 * 512; g = i - 262144;
    } else {
        if (i >= 331776) return;
        src = W; dst = W_bf; g = i - 266240;
    }
    float4 v = reinterpret_cast<const float4*>(src)[g];
    ushort4 o;
    o.x = f2bf(v.x); o.y = f2bf(v.y); o.z = f2bf(v.z); o.w = f2bf(v.w);
    reinterpret_cast<ushort4*>(dst)[g] = o;
}

// ---------------- A'[r][e][d] = E[e,d] * R[r,d]  (r-major layout) ----------------
__device__ __forceinline__ unsigned int mul2bf(unsigned int a, unsigned int b) {
    float a0 = bf2f(a & 0xffffu), a1 = bf2f(a >> 16);
    float b0 = bf2f(b & 0xffffu), b1 = bf2f(b >> 16);
    return (unsigned int)f2bf(a0 * b0) | ((unsigned int)f2bf(a1 * b1) << 16);
}

__global__ void build_ap(const unsigned short* __restrict__ G,
                         unsigned short* __restrict__ Ap) {
    int t = blockIdx.x * blockDim.x + threadIdx.x;
    int row = t >> 6;            // row = r*2048 + e
    int d = (t & 63) * 8;
    int r = row >> 11, e = row & 2047;
    const uint4 ev = *reinterpret_cast<const uint4*>(G + e * 512 + d);
    const uint4 rv = *reinterpret_cast<const uint4*>(G + (2048 + r) * 512 + d);
    uint4 o;
    o.x = mul2bf(ev.x, rv.x);
    o.y = mul2bf(ev.y, rv.y);
    o.z = mul2bf(ev.z, rv.z);
    o.w = mul2bf(ev.w, rv.w);
    *reinterpret_cast<uint4*>(Ap + (size_t)row * 512 + d) = o;
}

// ---------------- gate GEMM (m97 128^2 structure, known-good) ----------------
#define BM 128
#define BN 128
#define BK 64

template <bool GUARD_M, bool BIAS_BF16OUT>
__global__ __launch_bounds__(256, 2) void mfma_gemm_bt(
    const unsigned short* __restrict__ A,
    const unsigned short* __restrict__ Bt,
    const float* __restrict__ bias,
    void* __restrict__ Cout,
    int M, int N, int K) {
    __shared__ __align__(16) unsigned short As[BM * BK];
    __shared__ __align__(16) unsigned short Bs[BN * BK];

    const int tid = threadIdx.x;
    const int lane = tid & 63;
    const int wave = tid >> 6;
    const int nbn = N / BN;
    const int bm0 = (blockIdx.x / nbn) * BM;
    const int bn0 = (blockIdx.x % nbn) * BN;
    const int wr = wave >> 1, wc = wave & 1;

    f32x4 acc[4][4] = {};

    const int srow = wave * 32 + (lane >> 3);
    const int scol = (lane & 7) * 8;

    for (int kb = 0; kb < K; kb += BK) {
#pragma unroll
        for (int i = 0; i < 4; ++i) {
            int row = bm0 + srow + i * 8;
            if (GUARD_M) row = min(row, M - 1);
            const unsigned short* src = A + (size_t)row * K + kb + scol;
            unsigned short* dst = &As[(wave * 32 + i * 8) * BK];
            __builtin_amdgcn_global_load_lds(
                (const __attribute__((address_space(1))) void*)src,
                (__attribute__((address_space(3))) void*)dst, 16, 0, 0);
        }
#pragma unroll
        for (int i = 0; i < 4; ++i) {
            int row = bn0 + srow + i * 8;
            const unsigned short* src = Bt + (size_t)row * K + kb + scol;
            unsigned short* dst = &Bs[(wave * 32 + i * 8) * BK];
            __builtin_amdgcn_global_load_lds(
                (const __attribute__((address_space(1))) void*)src,
                (__attribute__((address_space(3))) void*)dst, 16, 0, 0);
        }
        __syncthreads();

#pragma unroll
        for (int ks = 0; ks < BK / 32; ++ks) {
            const int k0 = ks * 32 + (lane >> 4) * 8;
            bf16x8 av[4], bv[4];
#pragma unroll
            for (int m = 0; m < 4; ++m)
                av[m] = *reinterpret_cast<const bf16x8*>(
                    &As[(wr * 64 + m * 16 + (lane & 15)) * BK + k0]);
#pragma unroll
            for (int n = 0; n < 4; ++n)
                bv[n] = *reinterpret_cast<const bf16x8*>(
                    &Bs[(wc * 64 + n * 16 + (lane & 15)) * BK + k0]);
#pragma unroll
            for (int m = 0; m < 4; ++m)
#pragma unroll
                for (int n = 0; n < 4; ++n)
                    acc[m][n] = __builtin_amdgcn_mfma_f32_16x16x32_bf16(
                        av[m], bv[n], acc[m][n], 0, 0, 0);
        }
        __syncthreads();
    }

#pragma unroll
    for (int m = 0; m < 4; ++m) {
#pragma unroll
        for (int n = 0; n < 4; ++n) {
#pragma unroll
            for (int j = 0; j < 4; ++j) {
                int row = bm0 + wr * 64 + m * 16 + (lane >> 4) * 4 + j;
                int col = bn0 + wc * 64 + n * 16 + (lane & 15);
                if (GUARD_M && row >= M) continue;
                float v = acc[m][n][j];
                if (BIAS_BF16OUT) {
                    v += bias[col];
                    ((unsigned short*)Cout)[(size_t)row * N + col] = f2bf(v);
                } else {
                    ((float*)Cout)[(size_t)row * N + col] = v;
                }
            }
        }
    }
}

// ---------------- main GEMM: per-r symmetric, lower-triangle tiles ----------------
// For each r: S_r = A'_r @ E^T is symmetric 2048x2048. Compute tiles (ti,tj), tj<=ti,
// write direct tile; for ti!=tj also write transposed mirror via LDS transpose.
// C[e][r][f] at e*65536 + r*2048 + f.
#define NT8 8  // K / 64

__global__ __launch_bounds__(512, 2) void gemm256_tri(
    const unsigned short* __restrict__ Ap,  // [32][2048][512]
    const unsigned short* __restrict__ G,   // rows 0..2047 = E
    float* __restrict__ C) {
    __shared__ __align__(16) unsigned short lds[65536];  // 128 KiB

    const int tid = threadIdx.x;
    const int lane = tid & 63;
    const int wave = tid >> 6;   // 0..7
    const int wr = wave >> 2;    // 0..1 -> M half
    const int wc = wave & 3;     // 0..3 -> N quarter
    const int laneM = lane & 15;
    const int laneK = (lane >> 4) * 8;
    const int kx = (lane & 7) * 8;

    // XCD swizzle: 1152 blocks = 8 XCD x 144; each XCD owns 4 whole r-slices
    const int swz = (blockIdx.x & 7) * 144 + (blockIdx.x >> 3);
    const int r = swz / 36;
    int t = swz - r * 36;
    int ti = 0;
    while (t >= ti + 1) { t -= ti + 1; ++ti; }
    const int tj = t;                 // tj <= ti
    const int am0 = ti * 256;         // rows into A'_r
    const int bn0 = tj * 256;         // rows into E

    const unsigned short* Ar = Ap + (size_t)r * 2048 * 512;

    // staging coords: linear LDS dest, pre-swizzled global source (rule 21)
    const int sr0 = tid >> 3;                                   // row (+rd*64)
    const int sc = ((tid & 7) * 8) ^ (((tid >> 3) & 7) * 8);    // inverse-swizzled col

    auto STAGE = [&](const unsigned short* mat, int row0, int kb, int slotOff) {
#pragma unroll
        for (int rd = 0; rd < 2; ++rd) {
            const unsigned short* src = mat + (size_t)(row0 + sr0 + rd * 64) * 512 + kb + sc;
            unsigned short* dst = &lds[slotOff + wave * 512 + rd * 4096];  // wave-uniform
            __builtin_amdgcn_global_load_lds(
                (const __attribute__((address_space(1))) void*)src,
                (__attribute__((address_space(3))) void*)dst, 16, 0, 0);
        }
    };
    auto RD = [&](int slotOff, int rr, int ks) -> bf16x8 {
        return *reinterpret_cast<const bf16x8*>(
            &lds[slotOff + rr * 64 + (((ks * 32) + laneK) ^ kx)]);
    };
    // slots (ushort units): A(P,h)=P*32768+h*8192 ; B(P,h)=P*32768+16384+h*8192

    f32x4 acc[8][4] = {};
    bf16x8 av[4][2], bv0[2][2], bv1[2][2];

    // prologue: tile0 {A0,B0,B1,A1} + tile1 {B0,A0,B1}
    STAGE(Ar, am0,        0, 0 * 32768 + 0 * 8192);
    STAGE(G,  bn0,        0, 0 * 32768 + 16384 + 0 * 8192);
    STAGE(G,  bn0 + 128,  0, 0 * 32768 + 16384 + 1 * 8192);
    STAGE(Ar, am0 + 128,  0, 0 * 32768 + 1 * 8192);
    STAGE(G,  bn0,       64, 1 * 32768 + 16384 + 0 * 8192);
    STAGE(Ar, am0,       64, 1 * 32768 + 0 * 8192);
    STAGE(G,  bn0 + 128, 64, 1 * 32768 + 16384 + 1 * 8192);
    asm volatile("s_waitcnt vmcnt(6)" ::: "memory");
    __builtin_amdgcn_s_barrier();

#pragma unroll
    for (int tt = 0; tt < NT8; ++tt) {
        const int P = tt & 1;
        const int sA = P * 32768 + wr * 8192;
        const int sB = P * 32768 + 16384 + (wc >> 1) * 8192;
        const int rB = (wc & 1) * 64;

        // ===== phase 1: read A-mh0 + B-nh0; stage (tt+1)A1 =====
#pragma unroll
        for (int m = 0; m < 4; ++m)
#pragma unroll
            for (int ks = 0; ks < 2; ++ks)
                av[m][ks] = RD(sA, m * 16 + laneM, ks);
#pragma unroll
        for (int n = 0; n < 2; ++n)
#pragma unroll
            for (int ks = 0; ks < 2; ++ks)
                bv0[n][ks] = RD(sB, rB + n * 16 + laneM, ks);
        if (tt + 1 < NT8)
            STAGE(Ar, am0 + 128, (tt + 1) * 64, ((tt + 1) & 1) * 32768 + 8192);
        __builtin_amdgcn_s_barrier();
        asm volatile("s_waitcnt lgkmcnt(0)" ::: "memory");
        __builtin_amdgcn_sched_barrier(0);
        __builtin_amdgcn_s_setprio(1);
#pragma unroll
        for (int ks = 0; ks < 2; ++ks)
#pragma unroll
            for (int m = 0; m < 4; ++m)
#pragma unroll
                for (int n = 0; n < 2; ++n)
                    acc[m][n] = __builtin_amdgcn_mfma_f32_16x16x32_bf16(
                        av[m][ks], bv0[n][ks], acc[m][n], 0, 0, 0);
        __builtin_amdgcn_s_setprio(0);
        __builtin_amdgcn_s_barrier();

        // ===== phase 2: read B-nh1 =====
#pragma unroll
        for (int n = 0; n < 2; ++n)
#pragma unroll
            for (int ks = 0; ks < 2; ++ks)
                bv1[n][ks] = RD(sB, rB + (2 + n) * 16 + laneM, ks);
        __builtin_amdgcn_s_barrier();
        asm volatile("s_waitcnt lgkmcnt(0)" ::: "memory");
        __builtin_amdgcn_sched_barrier(0);
        __builtin_amdgcn_s_setprio(1);
#pragma unroll
        for (int ks = 0; ks < 2; ++ks)
#pragma unroll
            for (int m = 0; m < 4; ++m)
#pragma unroll
                for (int n = 0; n < 2; ++n)
                    acc[m][2 + n] = __builtin_amdgcn_mfma_f32_16x16x32_bf16(
                        av[m][ks], bv1[n][ks], acc[m][2 + n], 0, 0, 0);
        __builtin_amdgcn_s_setprio(0);
        __builtin_amdgcn_s_barrier();

        // ===== phase 3: read A-mh1; stage (tt+2)B0 =====
#pragma unroll
        for (int m = 0; m < 4; ++m)
#pragma unroll
            for (int ks = 0; ks < 2; ++ks)
                av[m][ks] = RD(sA, 64 + m * 16 + laneM, ks);
        if (tt + 2 < NT8)
            STAGE(G, bn0, (tt + 2) * 64, ((tt + 2) & 1) * 32768 + 16384);
        __builtin_amdgcn_s_barrier();
        asm volatile("s_waitcnt lgkmcnt(0)" ::: "memory");
        __builtin_amdgcn_sched_barrier(0);
        __builtin_amdgcn_s_setprio(1);
#pragma unroll
        for (int ks = 0; ks < 2; ++ks)
#pragma unroll
            for (int m = 0; m < 4; ++m)
#pragma unroll
                for (int n = 0; n < 2; ++n)
                    acc[4 + m][2 + n] = __builtin_amdgcn_mfma_f32_16x16x32_bf16(
                        av[m][ks], bv1[n][ks], acc[4 + m][2 + n], 0, 0, 0);
        __builtin_amdgcn_s_setprio(0);
        __builtin_amdgcn_s_barrier();

        // ===== phase 4: stage (tt+2)A0 + (tt+2)B1; MFMA from regs =====
        if (tt + 2 < NT8) {
            STAGE(Ar, am0, (tt + 2) * 64, ((tt + 2) & 1) * 32768);
            STAGE(G, bn0 + 128, (tt + 2) * 64, ((tt + 2) & 1) * 32768 + 16384 + 8192);
        }
        __builtin_amdgcn_s_barrier();
        __builtin_amdgcn_s_setprio(1);
#pragma unroll
        for (int ks = 0; ks < 2; ++ks)
#pragma unroll
            for (int m = 0; m < 4; ++m)
#pragma unroll
                for (int n = 0; n < 2; ++n)
                    acc[4 + m][n] = __builtin_amdgcn_mfma_f32_16x16x32_bf16(
                        av[m][ks], bv0[n][ks], acc[4 + m][n], 0, 0, 0);
        __builtin_amdgcn_s_setprio(0);
        if (tt < NT8 - 1) {
            if (tt == NT8 - 2)
                asm volatile("s_waitcnt vmcnt(0)" ::: "memory");
            else
                asm volatile("s_waitcnt vmcnt(6)" ::: "memory");
            __builtin_amdgcn_s_barrier();
        }
    }

    // ===== epilogue =====
    const size_t rOff = (size_t)r * 2048;

    // direct tile: C[e][r][f], e in ti-range, f in tj-range (nt stores)
#pragma unroll
    for (int mi = 0; mi < 8; ++mi)
#pragma unroll
        for (int ni = 0; ni < 4; ++ni)
#pragma unroll
            for (int jj = 0; jj < 4; ++jj) {
                int e = ti * 256 + wr * 128 + mi * 16 + (lane >> 4) * 4 + jj;
                int f = tj * 256 + wc * 64 + ni * 16 + laneM;
                __builtin_nontemporal_store(acc[mi][ni][jj],
                                            &C[(size_t)e * 65536 + rOff + f]);
            }

    // mirror tile via LDS transpose (off-diagonal only)
    if (ti != tj) {
        float* buf = (float*)lds;
#pragma unroll
        for (int h = 0; h < 2; ++h) {
            __syncthreads();  // LDS free (K-loop / previous half done)
            if (wr == h) {
                // waves of this row-half write their full acc: [128][256] f32
#pragma unroll
                for (int mi = 0; mi < 8; ++mi)
#pragma unroll
                    for (int ni = 0; ni < 4; ++ni)
#pragma unroll
                        for (int jj = 0; jj < 4; ++jj) {
                            int lrow = mi * 16 + (lane >> 4) * 4 + jj;
                            int lcol = wc * 64 + ni * 16 + laneM;
                            buf[lrow * 256 + (lcol ^ ((lrow & 12) << 2))] =
                                acc[mi][ni][jj];
                        }
            }
            __syncthreads();
            // transposed read + nt f32x4 store: C[f][r][e]
            const int fl = tid >> 1;             // 0..255: f within tile
            const int eb = (tid & 1) * 64;       // e-chunk within half
#pragma unroll
            for (int g = 0; g < 16; ++g) {
                const int e0 = eb + g * 4;
                const int sx = (e0 & 12) << 2;   // same for e0..e0+3
                f32x4 v;
                v[0] = buf[(e0 + 0) * 256 + (fl ^ sx)];
                v[1] = buf[(e0 + 1) * 256 + (fl ^ sx)];
                v[2] = buf[(e0 + 2) * 256 + (fl ^ sx)];
                v[3] = buf[(e0 + 3) * 256 + (fl ^ sx)];
                __builtin_nontemporal_store(
                    v, (f32x4*)&C[(size_t)(tj * 256 + fl) * 65536 + rOff +
                                  ti * 256 + h * 128 + e0]);
            }
        }
    }
}

// ---------------- launcher ----------------
extern "C" void kernel_launch(void* const* d_in, const int* in_sizes, int n_in,
                              void* d_out, int out_size, void* d_ws, size_t ws_size,
                              hipStream_t stream) {
    const float* entities  = (const float*)d_in[0];
    const float* relations = (const float*)d_in[1];
    const float* W         = (const float*)d_in[2];
    const float* b         = (const float*)d_in[3];

    char* ws = (char*)d_ws;
    unsigned short* W_bf = (unsigned short*)ws;
    unsigned short* X_bf = (unsigned short*)(ws + 524288);
    unsigned short* G_bf = (unsigned short*)(ws + 524288 + 2129920);
    unsigned short* Ap   = (unsigned short*)(ws + 524288 + 2129920 + 2129920);

    cast_all<<<1296, 256, 0, stream>>>(entities, relations, W, X_bf, W_bf);

    // gate GEMM: G[2080][512] = X @ W^T + b  (bf16 out)
    mfma_gemm_bt<true, true><<<17 * 4, 256, 0, stream>>>(
        X_bf, W_bf, b, (void*)G_bf, 2080, 512, 512);

    // A'[r][e][d] = E[e,d] * R[r,d]
    build_ap<<<16384, 256, 0, stream>>>(G_bf, Ap);

    // main GEMM: per-r symmetric lower-triangle (32 r x 36 tiles)
    gemm256_tri<<<1152, 512, 0, stream>>>(Ap, G_bf, (float*)d_out);
}

// Round 7
// 207.571 us; speedup vs baseline: 4.5731x; 4.5731x over previous
//
#include <hip/hip_runtime.h>

typedef __attribute__((ext_vector_type(8))) __bf16 bf16x8;
typedef __attribute__((ext_vector_type(4))) float f32x4;

__device__ __forceinline__ float bf2f(unsigned int u) {
    return __uint_as_float(u << 16);
}
__device__ __forceinline__ unsigned short f2bf(float f) {
    unsigned int x = __float_as_uint(f);
    return (unsigned short)((x + 0x7fffu + ((x >> 16) & 1u)) >> 16);
}

// ---------------- merged cast f32 -> bf16 ----------------
__global__ void cast_all(const float* __restrict__ ent, const float* __restrict__ rel,
                         const float* __restrict__ W,
                         unsigned short* __restrict__ X_bf,
                         unsigned short* __restrict__ W_bf) {
    int i = blockIdx.x * blockDim.x + threadIdx.x;
    const float* src;
    unsigned short* dst;
    int g;
    if (i < 262144) {
        src = ent; dst = X_bf; g = i;
    } else if (i < 266240) {
        src = rel; dst = X_bf + 2048 * 512; g = i - 262144;
    } else {
        if (i >= 331776) return;
        src = W; dst = W_bf; g = i - 266240;
    }
    float4 v = reinterpret_cast<const float4*>(src)[g];
    ushort4 o;
    o.x = f2bf(v.x); o.y = f2bf(v.y); o.z = f2bf(v.z); o.w = f2bf(v.w);
    reinterpret_cast<ushort4*>(dst)[g] = o;
}

// ---------------- A'[(e*32+r), d] = E[e,d] * R[r,d] (er-major) ----------------
__device__ __forceinline__ unsigned int mul2bf(unsigned int a, unsigned int b) {
    float a0 = bf2f(a & 0xffffu), a1 = bf2f(a >> 16);
    float b0 = bf2f(b & 0xffffu), b1 = bf2f(b >> 16);
    return (unsigned int)f2bf(a0 * b0) | ((unsigned int)f2bf(a1 * b1) << 16);
}

__global__ void build_ap(const unsigned short* __restrict__ G,
                         unsigned short* __restrict__ Ap) {
    int t = blockIdx.x * blockDim.x + threadIdx.x;
    int row = t >> 6;
    int d = (t & 63) * 8;
    int e = row >> 5, r = row & 31;
    const uint4 ev = *reinterpret_cast<const uint4*>(G + e * 512 + d);
    const uint4 rv = *reinterpret_cast<const uint4*>(G + (2048 + r) * 512 + d);
    uint4 o;
    o.x = mul2bf(ev.x, rv.x);
    o.y = mul2bf(ev.y, rv.y);
    o.z = mul2bf(ev.z, rv.z);
    o.w = mul2bf(ev.w, rv.w);
    *reinterpret_cast<uint4*>(Ap + (size_t)row * 512 + d) = o;
}

// ---------------- gate GEMM (m97 128^2 structure, known-good) ----------------
#define BM 128
#define BN 128
#define BK 64

template <bool GUARD_M, bool BIAS_BF16OUT>
__global__ __launch_bounds__(256, 2) void mfma_gemm_bt(
    const unsigned short* __restrict__ A,
    const unsigned short* __restrict__ Bt,
    const float* __restrict__ bias,
    void* __restrict__ Cout,
    int M, int N, int K) {
    __shared__ __align__(16) unsigned short As[BM * BK];
    __shared__ __align__(16) unsigned short Bs[BN * BK];

    const int tid = threadIdx.x;
    const int lane = tid & 63;
    const int wave = tid >> 6;
    const int nbn = N / BN;
    const int bm0 = (blockIdx.x / nbn) * BM;
    const int bn0 = (blockIdx.x % nbn) * BN;
    const int wr = wave >> 1, wc = wave & 1;

    f32x4 acc[4][4] = {};

    const int srow = wave * 32 + (lane >> 3);
    const int scol = (lane & 7) * 8;

    for (int kb = 0; kb < K; kb += BK) {
#pragma unroll
        for (int i = 0; i < 4; ++i) {
            int row = bm0 + srow + i * 8;
            if (GUARD_M) row = min(row, M - 1);
            const unsigned short* src = A + (size_t)row * K + kb + scol;
            unsigned short* dst = &As[(wave * 32 + i * 8) * BK];
            __builtin_amdgcn_global_load_lds(
                (const __attribute__((address_space(1))) void*)src,
                (__attribute__((address_space(3))) void*)dst, 16, 0, 0);
        }
#pragma unroll
        for (int i = 0; i < 4; ++i) {
            int row = bn0 + srow + i * 8;
            const unsigned short* src = Bt + (size_t)row * K + kb + scol;
            unsigned short* dst = &Bs[(wave * 32 + i * 8) * BK];
            __builtin_amdgcn_global_load_lds(
                (const __attribute__((address_space(1))) void*)src,
                (__attribute__((address_space(3))) void*)dst, 16, 0, 0);
        }
        __syncthreads();

#pragma unroll
        for (int ks = 0; ks < BK / 32; ++ks) {
            const int k0 = ks * 32 + (lane >> 4) * 8;
            bf16x8 av[4], bv[4];
#pragma unroll
            for (int m = 0; m < 4; ++m)
                av[m] = *reinterpret_cast<const bf16x8*>(
                    &As[(wr * 64 + m * 16 + (lane & 15)) * BK + k0]);
#pragma unroll
            for (int n = 0; n < 4; ++n)
                bv[n] = *reinterpret_cast<const bf16x8*>(
                    &Bs[(wc * 64 + n * 16 + (lane & 15)) * BK + k0]);
#pragma unroll
            for (int m = 0; m < 4; ++m)
#pragma unroll
                for (int n = 0; n < 4; ++n)
                    acc[m][n] = __builtin_amdgcn_mfma_f32_16x16x32_bf16(
                        av[m], bv[n], acc[m][n], 0, 0, 0);
        }
        __syncthreads();
    }

#pragma unroll
    for (int m = 0; m < 4; ++m) {
#pragma unroll
        for (int n = 0; n < 4; ++n) {
#pragma unroll
            for (int j = 0; j < 4; ++j) {
                int row = bm0 + wr * 64 + m * 16 + (lane >> 4) * 4 + j;
                int col = bn0 + wc * 64 + n * 16 + (lane & 15);
                if (GUARD_M && row >= M) continue;
                float v = acc[m][n][j];
                if (BIAS_BF16OUT) {
                    v += bias[col];
                    ((unsigned short*)Cout)[(size_t)row * N + col] = f2bf(v);
                } else {
                    ((float*)Cout)[(size_t)row * N + col] = v;
                }
            }
        }
    }
}

// ---------------- main GEMM: 256^2 tile, 8-phase, counted vmcnt ----------------
// C[65536][2048] = A'[65536][512] @ E[2048][512]^T
// Epilogue: transpose acc through LDS -> f32x4 nt stores (1KB/instr, 256B/row).
#define NT8 8  // K / 64

__global__ __launch_bounds__(512, 2) void gemm256_8ph(
    const unsigned short* __restrict__ A,  // [65536][512]
    const unsigned short* __restrict__ B,  // [2048][512] (= E rows of G)
    float* __restrict__ C) {
    __shared__ __align__(16) unsigned short lds[65536];  // 128 KiB

    const int tid = threadIdx.x;
    const int lane = tid & 63;
    const int wave = tid >> 6;   // 0..7
    const int wr = wave >> 2;    // 0..1 -> M half
    const int wc = wave & 3;     // 0..3 -> N quarter
    const int laneM = lane & 15;
    const int laneK = (lane >> 4) * 8;
    const int kx = (lane & 7) * 8;

    // XCD-aware swizzle (nwg=2048, divisible by 8)
    const int swz = (blockIdx.x & 7) * 256 + (blockIdx.x >> 3);
    const int bm0 = (swz >> 3) * 256;
    const int bn0 = (swz & 7) * 256;

    // staging coords: linear LDS dest, pre-swizzled global source (rule 21)
    const int sr0 = tid >> 3;                                   // row (+rd*64)
    const int sc = ((tid & 7) * 8) ^ (((tid >> 3) & 7) * 8);    // inverse-swizzled col

    auto STAGE = [&](const unsigned short* mat, int row0, int kb, int slotOff) {
#pragma unroll
        for (int rd = 0; rd < 2; ++rd) {
            const unsigned short* src = mat + (size_t)(row0 + sr0 + rd * 64) * 512 + kb + sc;
            unsigned short* dst = &lds[slotOff + wave * 512 + rd * 4096];  // wave-uniform
            __builtin_amdgcn_global_load_lds(
                (const __attribute__((address_space(1))) void*)src,
                (__attribute__((address_space(3))) void*)dst, 16, 0, 0);
        }
    };
    auto RD = [&](int slotOff, int r, int ks) -> bf16x8 {
        return *reinterpret_cast<const bf16x8*>(
            &lds[slotOff + r * 64 + (((ks * 32) + laneK) ^ kx)]);
    };
    // slots (ushort units): A(P,h)=P*32768+h*8192 ; B(P,h)=P*32768+16384+h*8192

    f32x4 acc[8][4] = {};
    bf16x8 av[4][2], bv0[2][2], bv1[2][2];

    // prologue: tile0 {A0,B0,B1,A1} + tile1 {B0,A0,B1}
    STAGE(A, bm0,        0, 0 * 32768 + 0 * 8192);
    STAGE(B, bn0,        0, 0 * 32768 + 16384 + 0 * 8192);
    STAGE(B, bn0 + 128,  0, 0 * 32768 + 16384 + 1 * 8192);
    STAGE(A, bm0 + 128,  0, 0 * 32768 + 1 * 8192);
    STAGE(B, bn0,       64, 1 * 32768 + 16384 + 0 * 8192);
    STAGE(A, bm0,       64, 1 * 32768 + 0 * 8192);
    STAGE(B, bn0 + 128, 64, 1 * 32768 + 16384 + 1 * 8192);
    asm volatile("s_waitcnt vmcnt(6)" ::: "memory");
    __builtin_amdgcn_s_barrier();

#pragma unroll
    for (int t = 0; t < NT8; ++t) {
        const int P = t & 1;
        const int sA = P * 32768 + wr * 8192;
        const int sB = P * 32768 + 16384 + (wc >> 1) * 8192;
        const int rB = (wc & 1) * 64;

        // ===== phase 1: read A-mh0 + B-nh0; stage (t+1)A1 =====
#pragma unroll
        for (int m = 0; m < 4; ++m)
#pragma unroll
            for (int ks = 0; ks < 2; ++ks)
                av[m][ks] = RD(sA, m * 16 + laneM, ks);
#pragma unroll
        for (int n = 0; n < 2; ++n)
#pragma unroll
            for (int ks = 0; ks < 2; ++ks)
                bv0[n][ks] = RD(sB, rB + n * 16 + laneM, ks);
        if (t + 1 < NT8)
            STAGE(A, bm0 + 128, (t + 1) * 64, ((t + 1) & 1) * 32768 + 8192);
        __builtin_amdgcn_s_barrier();
        asm volatile("s_waitcnt lgkmcnt(0)" ::: "memory");
        __builtin_amdgcn_sched_barrier(0);
        __builtin_amdgcn_s_setprio(1);
#pragma unroll
        for (int ks = 0; ks < 2; ++ks)
#pragma unroll
            for (int m = 0; m < 4; ++m)
#pragma unroll
                for (int n = 0; n < 2; ++n)
                    acc[m][n] = __builtin_amdgcn_mfma_f32_16x16x32_bf16(
                        av[m][ks], bv0[n][ks], acc[m][n], 0, 0, 0);
        __builtin_amdgcn_s_setprio(0);
        __builtin_amdgcn_s_barrier();

        // ===== phase 2: read B-nh1 =====
#pragma unroll
        for (int n = 0; n < 2; ++n)
#pragma unroll
            for (int ks = 0; ks < 2; ++ks)
                bv1[n][ks] = RD(sB, rB + (2 + n) * 16 + laneM, ks);
        __builtin_amdgcn_s_barrier();
        asm volatile("s_waitcnt lgkmcnt(0)" ::: "memory");
        __builtin_amdgcn_sched_barrier(0);
        __builtin_amdgcn_s_setprio(1);
#pragma unroll
        for (int ks = 0; ks < 2; ++ks)
#pragma unroll
            for (int m = 0; m < 4; ++m)
#pragma unroll
                for (int n = 0; n < 2; ++n)
                    acc[m][2 + n] = __builtin_amdgcn_mfma_f32_16x16x32_bf16(
                        av[m][ks], bv1[n][ks], acc[m][2 + n], 0, 0, 0);
        __builtin_amdgcn_s_setprio(0);
        __builtin_amdgcn_s_barrier();

        // ===== phase 3: read A-mh1; stage (t+2)B0 =====
#pragma unroll
        for (int m = 0; m < 4; ++m)
#pragma unroll
            for (int ks = 0; ks < 2; ++ks)
                av[m][ks] = RD(sA, 64 + m * 16 + laneM, ks);
        if (t + 2 < NT8)
            STAGE(B, bn0, (t + 2) * 64, ((t + 2) & 1) * 32768 + 16384);
        __builtin_amdgcn_s_barrier();
        asm volatile("s_waitcnt lgkmcnt(0)" ::: "memory");
        __builtin_amdgcn_sched_barrier(0);
        __builtin_amdgcn_s_setprio(1);
#pragma unroll
        for (int ks = 0; ks < 2; ++ks)
#pragma unroll
            for (int m = 0; m < 4; ++m)
#pragma unroll
                for (int n = 0; n < 2; ++n)
                    acc[4 + m][2 + n] = __builtin_amdgcn_mfma_f32_16x16x32_bf16(
                        av[m][ks], bv1[n][ks], acc[4 + m][2 + n], 0, 0, 0);
        __builtin_amdgcn_s_setprio(0);
        __builtin_amdgcn_s_barrier();

        // ===== phase 4: stage (t+2)A0 + (t+2)B1; MFMA from regs =====
        if (t + 2 < NT8) {
            STAGE(A, bm0, (t + 2) * 64, ((t + 2) & 1) * 32768);
            STAGE(B, bn0 + 128, (t + 2) * 64, ((t + 2) & 1) * 32768 + 16384 + 8192);
        }
        __builtin_amdgcn_s_barrier();
        __builtin_amdgcn_s_setprio(1);
#pragma unroll
        for (int ks = 0; ks < 2; ++ks)
#pragma unroll
            for (int m = 0; m < 4; ++m)
#pragma unroll
                for (int n = 0; n < 2; ++n)
                    acc[4 + m][n] = __builtin_amdgcn_mfma_f32_16x16x32_bf16(
                        av[m][ks], bv0[n][ks], acc[4 + m][n], 0, 0, 0);
        __builtin_amdgcn_s_setprio(0);
        if (t < NT8 - 1) {
            if (t == NT8 - 2)
                asm volatile("s_waitcnt vmcnt(0)" ::: "memory");
            else
                asm volatile("s_waitcnt vmcnt(6)" ::: "memory");
            __builtin_amdgcn_s_barrier();
        }
    }

    // ===== epilogue: transpose acc through LDS -> f32x4 nt stores =====
    // acc C/D layout: global row = bm0 + wr*128 + mi*16 + q*4 + j (q=lane>>4),
    //                 global col = bn0 + wc*64 + ni*16 + laneM.
    // Pass p handles mi in [p*4, p*4+4) -> LDS [128][256] f32 (full 128 KiB),
    // LDS row L = wr*64 + (mi&3)*16 + q*4 + j ; XOR-swizzle f ^ ((L&12)<<2).
    {
        float* buf = (float*)lds;
        const int q = lane >> 4;
#pragma unroll
        for (int pass = 0; pass < 2; ++pass) {
            __syncthreads();
#pragma unroll
            for (int mi = 0; mi < 4; ++mi)
#pragma unroll
                for (int ni = 0; ni < 4; ++ni)
#pragma unroll
                    for (int j = 0; j < 4; ++j) {
                        int L = wr * 64 + mi * 16 + q * 4 + j;
                        int fl = wc * 64 + ni * 16 + laneM;
                        buf[L * 256 + (fl ^ ((L & 12) << 2))] =
                            acc[pass * 4 + mi][ni][j];
                    }
            __syncthreads();
            // each wave stores 16 rows; per instruction: 4 rows x 256B contiguous
#pragma unroll
            for (int rr = 0; rr < 4; ++rr) {
                int R = wave * 16 + rr * 4 + q;
                int er = bm0 + (R & 63) + (R >> 6) * 128 + pass * 64;
                float* dstRow = C + (size_t)er * 2048 + bn0;
#pragma unroll
                for (int g = 0; g < 4; ++g) {
                    int fl = g * 64 + laneM * 4;
                    int fs = fl ^ ((R & 12) << 2);
                    f32x4 v = *reinterpret_cast<const f32x4*>(&buf[R * 256 + fs]);
                    __builtin_nontemporal_store(v, (f32x4*)(dstRow + fl));
                }
            }
        }
    }
}

// ---------------- launcher ----------------
extern "C" void kernel_launch(void* const* d_in, const int* in_sizes, int n_in,
                              void* d_out, int out_size, void* d_ws, size_t ws_size,
                              hipStream_t stream) {
    const float* entities  = (const float*)d_in[0];
    const float* relations = (const float*)d_in[1];
    const float* W         = (const float*)d_in[2];
    const float* b         = (const float*)d_in[3];

    char* ws = (char*)d_ws;
    unsigned short* W_bf = (unsigned short*)ws;
    unsigned short* X_bf = (unsigned short*)(ws + 524288);
    unsigned short* G_bf = (unsigned short*)(ws + 524288 + 2129920);
    unsigned short* Ap   = (unsigned short*)(ws + 524288 + 2129920 + 2129920);

    cast_all<<<1296, 256, 0, stream>>>(entities, relations, W, X_bf, W_bf);

    // gate GEMM: G[2080][512] = X @ W^T + b  (bf16 out)
    mfma_gemm_bt<true, true><<<17 * 4, 256, 0, stream>>>(
        X_bf, W_bf, b, (void*)G_bf, 2080, 512, 512);

    // A'[(e*32+r), d] = E[e,d] * R[r,d]
    build_ap<<<16384, 256, 0, stream>>>(G_bf, Ap);

    // main GEMM: out[65536][2048] = A' @ E^T
    gemm256_8ph<<<2048, 512, 0, stream>>>(Ap, G_bf, (float*)d_out);
}